// Round 3
// baseline (391.073 us; speedup 1.0000x reference)
//
#include <hip/hip_runtime.h>
#include <hip/hip_bf16.h>
#include <cstdint>

#define NN 2000   // nodes
#define NB 32     // batch
#define DD 32     // d_in == d_out
#define HH 64     // hidden
#define EE 16     // env features
#define NP 24     // periods
#define MAXNZ 256 // per-row nnz storage capacity (mean ~100, sd ~10)
#define NSLOT 20  // register slots per thread in k_conv phase 2 (covers c <= 160)

// ---- env = relu(env_features @ W_env + b) ; Tm[p] = tgt_emb[p] + env (fused) ----
__global__ __launch_bounds__(64) void k_envtm(const float* __restrict__ envf,
                                              const float* __restrict__ Wenv,
                                              const float* __restrict__ benv,
                                              const float* __restrict__ tgt,
                                              float* __restrict__ env,
                                              float* __restrict__ Tm) {
    int n = blockIdx.x, h = threadIdx.x;
    float acc = benv[h];
#pragma unroll
    for (int e = 0; e < EE; ++e) acc = fmaf(envf[n * EE + e], Wenv[e * HH + h], acc);
    acc = fmaxf(acc, 0.f);
    env[n * HH + h] = acc;
#pragma unroll
    for (int p = 0; p < NP; ++p) {
        size_t o = ((size_t)p * NN + n) * HH + h;
        Tm[o] = tgt[o] + acc;
    }
}

// ------- support = x @ W ; residual = relu(x @ Wres + bres) : [NB*NN, DD] each -------
__global__ __launch_bounds__(256) void k_supp_res(const float* __restrict__ x,
                                                  const float* __restrict__ W,
                                                  const float* __restrict__ Wres,
                                                  const float* __restrict__ bres,
                                                  float* __restrict__ supp,
                                                  float* __restrict__ resd) {
    __shared__ float w[DD * DD], wr[DD * DD];
    for (int i = threadIdx.x; i < DD * DD; i += 256) { w[i] = W[i]; wr[i] = Wres[i]; }
    __syncthreads();
    int idx = blockIdx.x * 256 + threadIdx.x;
    if (idx >= NB * NN) return;
    float xv[DD];
    const float4* xr = (const float4*)(x + (size_t)idx * DD);
#pragma unroll
    for (int q = 0; q < DD / 4; ++q) {
        float4 v = xr[q];
        xv[4 * q] = v.x; xv[4 * q + 1] = v.y; xv[4 * q + 2] = v.z; xv[4 * q + 3] = v.w;
    }
    float sa[DD], ra[DD];
#pragma unroll
    for (int m = 0; m < DD; ++m) { sa[m] = 0.f; ra[m] = bres[m]; }
#pragma unroll
    for (int d = 0; d < DD; ++d) {
        float xd = xv[d];
#pragma unroll
        for (int m = 0; m < DD; ++m) {
            sa[m] = fmaf(xd, w[d * DD + m], sa[m]);
            ra[m] = fmaf(xd, wr[d * DD + m], ra[m]);
        }
    }
    float4* so = (float4*)(supp + (size_t)idx * DD);
    float4* ro = (float4*)(resd + (size_t)idx * DD);
#pragma unroll
    for (int q = 0; q < DD / 4; ++q) {
        so[q] = make_float4(sa[4 * q], sa[4 * q + 1], sa[4 * q + 2], sa[4 * q + 3]);
        ro[q] = make_float4(fmaxf(ra[4 * q], 0.f), fmaxf(ra[4 * q + 1], 0.f),
                            fmaxf(ra[4 * q + 2], 0.f), fmaxf(ra[4 * q + 3], 0.f));
    }
}

// ---------------- compact adj rows: kidx/kval lists + counts ----------------
__global__ __launch_bounds__(256) void k_sparse(const float* __restrict__ adj,
                                                int* __restrict__ kidx,
                                                float* __restrict__ kval,
                                                int* __restrict__ cnt) {
    __shared__ int c;
    if (threadIdx.x == 0) c = 0;
    __syncthreads();
    int n = blockIdx.x;
    for (int k = threadIdx.x; k < NN; k += 256) {
        float v = adj[(size_t)n * NN + k];
        if (v > 0.f) {
            int p = atomicAdd(&c, 1);
            if (p < MAXNZ) { kidx[n * MAXNZ + p] = k; kval[n * MAXNZ + p] = v; }
        }
    }
    __syncthreads();
    if (threadIdx.x == 0) cnt[n] = min(c, MAXNZ);
}

// ---------------- period -> batch lists ----------------
__global__ __launch_bounds__(64) void k_periods(const int* __restrict__ cyc,
                                                int* __restrict__ pcnt,
                                                int* __restrict__ plist) {
    __shared__ int c[NP];
    __shared__ int l[NP * NB];
    int t = threadIdx.x;
    if (t < NP) c[t] = 0;
    for (int i = t; i < NP * NB; i += 64) l[i] = 0;
    __syncthreads();
    if (t < NB) {
        int p = cyc[t] % NP; if (p < 0) p += NP;
        int s = atomicAdd(&c[p], 1);
        l[p * NB + s] = t;
    }
    __syncthreads();
    if (t < NP) pcnt[t] = c[t];
    for (int i = t; i < NP * NB; i += 64) plist[i] = l[i];
}

// ---------------- main: per (p, n): sparse A row -> conv -> epilogue ----------------
__global__ __launch_bounds__(256) void k_conv(const float* __restrict__ src,   // [NP,NN,HH]
                                              const float* __restrict__ Tm,    // [NP,NN,HH]
                                              const float* __restrict__ env,   // [NN,HH]
                                              const float* __restrict__ supp,  // [NB,NN,DD]
                                              const float* __restrict__ resd,  // [NB,NN,DD]
                                              const float* __restrict__ bias,  // [DD]
                                              const int* __restrict__ kidx,
                                              const float* __restrict__ kval,
                                              const int* __restrict__ cnt,
                                              const int* __restrict__ pcnt,
                                              const int* __restrict__ plist,
                                              float* __restrict__ out) {
    int bi = blockIdx.x;
    int p = bi / NN;
    int n = bi - p * NN;
    int nb = pcnt[p];
    if (nb == 0) return;                       // inactive period: nothing to do
    __shared__ float avals[MAXNZ];
    __shared__ int kks[MAXNZ];
    __shared__ float part[128];                // 4 waves x 32 outputs
    int t = threadIdx.x;
    int c = cnt[n];

    // ---- phase 1: one 16-lane group per nonzero; coalesced 256 B row loads ----
    int gq = t >> 4, lq = t & 15;              // 16 groups of 16 lanes
    // S fragment (this lane's 4 h-values), broadcast across groups via L1
    float4 sv = ((const float4*)(src + ((size_t)p * NN + n) * HH))[lq];
    float4 ev = ((const float4*)(env + (size_t)n * HH))[lq];
    float s0 = sv.x + ev.x, s1 = sv.y + ev.y, s2 = sv.z + ev.z, s3 = sv.w + ev.w;
    for (int j0 = 0; j0 < c; j0 += 16) {       // uniform trip count (c is block-uniform)
        int j = j0 + gq;
        float acc = 0.f, kv = 0.f; int k = 0;
        if (j < c) {
            k  = kidx[n * MAXNZ + j];
            kv = kval[n * MAXNZ + j];
            float4 tv = ((const float4*)(Tm + ((size_t)p * NN + k) * HH))[lq];
            acc = tv.x * s0;
            acc = fmaf(tv.y, s1, acc);
            acc = fmaf(tv.z, s2, acc);
            acc = fmaf(tv.w, s3, acc);
        }
        acc += __shfl_xor(acc, 1);             // reduce within the 16-lane group
        acc += __shfl_xor(acc, 2);
        acc += __shfl_xor(acc, 4);
        acc += __shfl_xor(acc, 8);
        if (j < c && lq == 0) { avals[j] = fmaxf(acc, 0.f) * kv; kks[j] = k; }
    }
    __syncthreads();

    // ---- phase 2: conv over batches of this period + epilogue ----
    int m = t & 31, g = t >> 5;                // 8 j-groups x 32 outputs
    int wv = t >> 6;                           // wave id 0..3

    // register-preload this thread's j-list (static indices via full unroll)
    int jk[NSLOT]; float ja[NSLOT];
#pragma unroll
    for (int u = 0; u < NSLOT; ++u) {
        int j = g + (u << 3);
        bool v = j < c;
        int jj = v ? j : 0;
        jk[u] = kks[jj];
        ja[u] = v ? avals[jj] : 0.f;
    }

    for (int ib = 0; ib < nb; ++ib) {
        int b = plist[p * NB + ib];
        const float* sb = supp + (size_t)b * NN * DD + m;
        float vv[NSLOT];
#pragma unroll
        for (int u = 0; u < NSLOT; ++u) vv[u] = sb[(size_t)jk[u] * DD];  // independent, coalesced/32
        float acc = 0.f;
#pragma unroll
        for (int u = 0; u < NSLOT; ++u) acc = fmaf(ja[u], vv[u], acc);
        for (int j = NSLOT * 8 + g; j < c; j += 8)                       // tail (normally empty)
            acc = fmaf(avals[j], sb[(size_t)kks[j] * DD], acc);
        acc += __shfl_xor(acc, 32);            // combine the two 32-groups in each wave
        if ((t & 63) < 32) part[wv * 32 + m] = acc;
        __syncthreads();
        if (t < DD) {
            float s = bias[t] + part[t] + part[32 + t] + part[64 + t] + part[96 + t];
            size_t o = ((size_t)b * NN + n) * DD + t;
            out[o] = fmaxf(s + resd[o], 0.f);
        }
        __syncthreads();                       // part[] reused next batch
    }
}

extern "C" void kernel_launch(void* const* d_in, const int* in_sizes, int n_in,
                              void* d_out, int out_size, void* d_ws, size_t ws_size,
                              hipStream_t stream) {
    const float* x    = (const float*)d_in[0];
    const int*   cyc  = (const int*)d_in[1];
    const float* adj  = (const float*)d_in[2];
    const float* envf = (const float*)d_in[3];
    const float* Wenv = (const float*)d_in[4];
    const float* benv = (const float*)d_in[5];
    const float* src  = (const float*)d_in[6];
    const float* tgt  = (const float*)d_in[7];
    const float* W    = (const float*)d_in[8];
    const float* bias = (const float*)d_in[9];
    const float* Wres = (const float*)d_in[10];
    const float* bres = (const float*)d_in[11];
    float* out = (float*)d_out;
    char* ws = (char*)d_ws;

    // ws layout (bytes), all 16B-aligned; total ~33.3 MB
    int*   kidx = (int*)(ws + 0);                 // 2,048,000
    float* kval = (float*)(ws + 2048000);         // 2,048,000
    int*   cntw = (int*)(ws + 4096000);           //     8,000
    float* env  = (float*)(ws + 4104000);         //   512,000
    float* supp = (float*)(ws + 4616000);         // 8,192,000
    float* resd = (float*)(ws + 12808000);        // 8,192,000
    float* Tm   = (float*)(ws + 21000000);        // 12,288,000
    int*   pcnt = (int*)(ws + 33288000);          //        96
    int*   plist= (int*)(ws + 33288096);          //     3,072

    hipLaunchKernelGGL(k_envtm, dim3(NN), dim3(HH), 0, stream, envf, Wenv, benv, tgt, env, Tm);
    hipLaunchKernelGGL(k_supp_res, dim3((NB * NN + 255) / 256), dim3(256), 0, stream,
                       x, W, Wres, bres, supp, resd);
    hipLaunchKernelGGL(k_sparse, dim3(NN), dim3(256), 0, stream, adj, kidx, kval, cntw);
    hipLaunchKernelGGL(k_periods, dim3(1), dim3(64), 0, stream, cyc, pcnt, plist);
    hipLaunchKernelGGL(k_conv, dim3(NP * NN), dim3(256), 0, stream,
                       src, Tm, env, supp, resd, bias, kidx, kval, cntw, pcnt, plist, out);
}

// Round 5
// 342.685 us; speedup vs baseline: 1.1412x; 1.1412x over previous
//
#include <hip/hip_runtime.h>
#include <hip/hip_bf16.h>
#include <cstdint>

#define NN 2000   // nodes
#define NNP 2048  // padded nodes
#define NB 32     // batch
#define DD 32     // d_in == d_out
#define HH 64     // hidden
#define EE 16     // env features
#define NP 24     // periods
#define NBB 4     // batches per block
#define BCH 8     // max batch-chunks per period (worst case 32/4)
#define NT 32     // n-tiles of 64 (covers 2048)
#define LSTR 68   // LDS row stride in f16 elems (pad 4: breaks 128B-row bank aliasing)

typedef _Float16 f16;
typedef _Float16 half8 __attribute__((ext_vector_type(8)));
typedef _Float16 half4v __attribute__((ext_vector_type(4)));
typedef float f32x4 __attribute__((ext_vector_type(4)));

// ---- prologue A: env = relu(envf@Wenv+b); Sb/Tb = f16(src/tgt + env), zero-padded ----
__global__ __launch_bounds__(64) void k_prep(const float* __restrict__ envf,
                                             const float* __restrict__ Wenv,
                                             const float* __restrict__ benv,
                                             const float* __restrict__ src,
                                             const float* __restrict__ tgt,
                                             f16* __restrict__ Sb,
                                             f16* __restrict__ Tb) {
    int n = blockIdx.x, h = threadIdx.x;
    if (n >= NN) {                              // zero the pad rows 2000..2047
        for (int p = 0; p < NP; ++p) {
            size_t o = ((size_t)p * NNP + n) * HH + h;
            Sb[o] = (f16)0.f; Tb[o] = (f16)0.f;
        }
        return;
    }
    float acc = benv[h];
#pragma unroll
    for (int e = 0; e < EE; ++e) acc = fmaf(envf[n * EE + e], Wenv[e * HH + h], acc);
    acc = fmaxf(acc, 0.f);
    for (int p = 0; p < NP; ++p) {
        size_t i = ((size_t)p * NN + n) * HH + h;
        size_t o = ((size_t)p * NNP + n) * HH + h;
        Sb[o] = (f16)(src[i] + acc);
        Tb[o] = (f16)(tgt[i] + acc);
    }
}

// ---- prologue B: suppT[b][m][k] = f16(x@W), k zero-padded; resd = relu(x@Wres+bres) f32 ----
__global__ __launch_bounds__(256) void k_suppT(const float* __restrict__ x,
                                               const float* __restrict__ W,
                                               const float* __restrict__ Wres,
                                               const float* __restrict__ bres,
                                               f16* __restrict__ suppT,
                                               float* __restrict__ resd) {
    __shared__ float w[DD * DD], wr[DD * DD];
    for (int i = threadIdx.x; i < DD * DD; i += 256) { w[i] = W[i]; wr[i] = Wres[i]; }
    __syncthreads();
    int idx = blockIdx.x * 256 + threadIdx.x;   // b*2048 + node
    int b = idx >> 11, node = idx & (NNP - 1);
    if (node >= NN) {                           // zero-pad k dim
#pragma unroll
        for (int m = 0; m < DD; ++m) suppT[((size_t)b * DD + m) * NNP + node] = (f16)0.f;
        return;
    }
    float xv[DD];
    const float4* xr = (const float4*)(x + ((size_t)b * NN + node) * DD);
#pragma unroll
    for (int q = 0; q < DD / 4; ++q) {
        float4 v = xr[q];
        xv[4 * q] = v.x; xv[4 * q + 1] = v.y; xv[4 * q + 2] = v.z; xv[4 * q + 3] = v.w;
    }
    float sa[DD], ra[DD];
#pragma unroll
    for (int m = 0; m < DD; ++m) { sa[m] = 0.f; ra[m] = bres[m]; }
#pragma unroll
    for (int d = 0; d < DD; ++d) {
        float xd = xv[d];
#pragma unroll
        for (int m = 0; m < DD; ++m) {
            sa[m] = fmaf(xd, w[d * DD + m], sa[m]);
            ra[m] = fmaf(xd, wr[d * DD + m], ra[m]);
        }
    }
#pragma unroll
    for (int m = 0; m < DD; ++m)                // per-m coalesced along node
        suppT[((size_t)b * DD + m) * NNP + node] = (f16)sa[m];
    float4* ro = (float4*)(resd + ((size_t)b * NN + node) * DD);
#pragma unroll
    for (int q = 0; q < DD / 4; ++q)
        ro[q] = make_float4(fmaxf(ra[4 * q], 0.f), fmaxf(ra[4 * q + 1], 0.f),
                            fmaxf(ra[4 * q + 2], 0.f), fmaxf(ra[4 * q + 3], 0.f));
}

// ---- main: fused (S Tt^T -> relu*adj -> *supp) via f16 MFMA, f32 accumulate ----
__global__ __launch_bounds__(256) void k_conv2(const f16* __restrict__ Sb,    // [NP,NNP,HH]
                                               const f16* __restrict__ Tb,    // [NP,NNP,HH]
                                               const f16* __restrict__ suppT, // [NB,DD,NNP]
                                               const float* __restrict__ adj, // [NN,NN]
                                               const float* __restrict__ resd,// [NB,NN,DD]
                                               const float* __restrict__ bias,// [DD]
                                               const int* __restrict__ cyc,   // [NB]
                                               float* __restrict__ out) {
    int bi = blockIdx.x;
    int p = bi % NP;                 // p fastest: consecutive blocks share adj tiles in L2
    int rest = bi / NP;
    int bc = rest % BCH;
    int nt = rest / BCH;
    int b0 = bc * NBB;

    // uniform scan: batches belonging to period p (replaces k_periods)
    int c = 0, bs0 = 0, bs1 = 0, bs2 = 0, bs3 = 0;
    for (int b = 0; b < NB; ++b) {
        int per = cyc[b] % NP;
        if (per == p) {
            if (c == b0)          bs0 = b;
            else if (c == b0 + 1) bs1 = b;
            else if (c == b0 + 2) bs2 = b;
            else if (c == b0 + 3) bs3 = b;
            ++c;
        }
    }
    if (b0 >= c) return;
    int nb = min(NBB, c - b0);
    int bs[NBB] = {bs0, bs1, bs2, bs3};

    __shared__ f16 Tt[64][LSTR];
    __shared__ f16 Pt[64][LSTR];
    __shared__ f16 Sup[NBB][DD][LSTR];

    int t = threadIdx.x;
    int w = t >> 6, l = t & 63;
    int u = l & 15, g = l >> 4;      // MFMA lane decomposition
    int wm = w * 16;                 // wave's 16-row slice
    int n0 = nt * 64;

    // GEMM1 A-fragments (S rows), invariant over k-loop. k-map f: h = 32s + 8g + j
    const f16* sbase = Sb + ((size_t)p * NNP + n0 + wm + u) * HH + 8 * g;
    half8 af0 = *(const half8*)(sbase);
    half8 af1 = *(const half8*)(sbase + 32);

    float bias0 = bias[u], bias1 = bias[16 + u];

    f32x4 acc[NBB][2];
#pragma unroll
    for (int i = 0; i < NBB; ++i)
#pragma unroll
        for (int c2 = 0; c2 < 2; ++c2) acc[i][c2] = (f32x4){0.f, 0.f, 0.f, 0.f};

    for (int kt = 0; kt < NNP / 64; ++kt) {
        int k0 = kt * 64;
        __syncthreads();                        // prev iter done reading LDS
        {   // stage Tt: 64 rows x 128B; 4 threads/row x 16 f16 each (FULL row)
            int row = t >> 2, ch = t & 3;
            const half4v* gp = (const half4v*)(Tb + ((size_t)p * NNP + k0 + row) * HH + ch * 16);
            half4v v0 = gp[0], v1 = gp[1], v2 = gp[2], v3 = gp[3];
            *(half4v*)&Tt[row][ch * 16]      = v0;
            *(half4v*)&Tt[row][ch * 16 + 4]  = v1;
            *(half4v*)&Tt[row][ch * 16 + 8]  = v2;
            *(half4v*)&Tt[row][ch * 16 + 12] = v3;
        }
        {   // stage Sup[i]: 32 rows x 128B each; 8 threads/row x 8 f16
            int m = t >> 3, ch = t & 7;
#pragma unroll
            for (int i = 0; i < NBB; ++i) if (i < nb) {
                const half4v* gp = (const half4v*)(suppT + ((size_t)bs[i] * DD + m) * NNP + k0 + ch * 8);
                half4v v0 = gp[0], v1 = gp[1];
                *(half4v*)&Sup[i][m][ch * 8] = v0;
                *(half4v*)&Sup[i][m][ch * 8 + 4] = v1;
            }
        }
        __syncthreads();
        // GEMM1: P = S·T^T over h (K=64 = 2 MFMA), then relu*adj -> Pt (f16)
#pragma unroll
        for (int cc = 0; cc < 4; ++cc) {
            half4v b0lo = *(const half4v*)&Tt[16 * cc + u][8 * g];
            half4v b0hi = *(const half4v*)&Tt[16 * cc + u][8 * g + 4];
            half4v b1lo = *(const half4v*)&Tt[16 * cc + u][32 + 8 * g];
            half4v b1hi = *(const half4v*)&Tt[16 * cc + u][32 + 8 * g + 4];
            half8 bf0 = {b0lo[0], b0lo[1], b0lo[2], b0lo[3], b0hi[0], b0hi[1], b0hi[2], b0hi[3]};
            half8 bf1 = {b1lo[0], b1lo[1], b1lo[2], b1lo[3], b1hi[0], b1hi[1], b1hi[2], b1hi[3]};
            f32x4 pacc = (f32x4){0.f, 0.f, 0.f, 0.f};
            pacc = __builtin_amdgcn_mfma_f32_16x16x32_f16(af0, bf0, pacc, 0, 0, 0);
            pacc = __builtin_amdgcn_mfma_f32_16x16x32_f16(af1, bf1, pacc, 0, 0, 0);
            int kcol = k0 + 16 * cc + u;
#pragma unroll
            for (int r = 0; r < 4; ++r) {       // D layout: row = 4g+r, col = u (m89)
                int nrow = n0 + wm + 4 * g + r;
                float av = 0.f;
                if (nrow < NN && kcol < NN) av = adj[(size_t)nrow * NN + kcol];
                Pt[wm + 4 * g + r][16 * cc + u] = (f16)(fmaxf(pacc[r], 0.f) * av);
            }
        }
        __syncthreads();
        // GEMM2: acc += Pt · Sup  (K=64 = 2 MFMA steps)
#pragma unroll
        for (int s = 0; s < 2; ++s) {
            half4v plo = *(const half4v*)&Pt[wm + u][32 * s + 8 * g];
            half4v phi = *(const half4v*)&Pt[wm + u][32 * s + 8 * g + 4];
            half8 paf = {plo[0], plo[1], plo[2], plo[3], phi[0], phi[1], phi[2], phi[3]};
#pragma unroll
            for (int i = 0; i < NBB; ++i) if (i < nb) {
#pragma unroll
                for (int c2 = 0; c2 < 2; ++c2) {
                    half4v slo = *(const half4v*)&Sup[i][16 * c2 + u][32 * s + 8 * g];
                    half4v shi = *(const half4v*)&Sup[i][16 * c2 + u][32 * s + 8 * g + 4];
                    half8 sbf = {slo[0], slo[1], slo[2], slo[3], shi[0], shi[1], shi[2], shi[3]};
                    acc[i][c2] = __builtin_amdgcn_mfma_f32_16x16x32_f16(paf, sbf, acc[i][c2], 0, 0, 0);
                }
            }
        }
    }
    // epilogue: out = relu(acc + bias + resd)
#pragma unroll
    for (int i = 0; i < NBB; ++i) if (i < nb) {
        int b = bs[i];
#pragma unroll
        for (int c2 = 0; c2 < 2; ++c2) {
            float bv = c2 ? bias1 : bias0;
#pragma unroll
            for (int r = 0; r < 4; ++r) {
                int nrow = n0 + wm + 4 * g + r;
                if (nrow < NN) {
                    size_t o = ((size_t)b * NN + nrow) * DD + 16 * c2 + u;
                    out[o] = fmaxf(acc[i][c2][r] + bv + resd[o], 0.f);
                }
            }
        }
    }
}

extern "C" void kernel_launch(void* const* d_in, const int* in_sizes, int n_in,
                              void* d_out, int out_size, void* d_ws, size_t ws_size,
                              hipStream_t stream) {
    const float* x    = (const float*)d_in[0];
    const int*   cyc  = (const int*)d_in[1];
    const float* adj  = (const float*)d_in[2];
    const float* envf = (const float*)d_in[3];
    const float* Wenv = (const float*)d_in[4];
    const float* benv = (const float*)d_in[5];
    const float* src  = (const float*)d_in[6];
    const float* tgt  = (const float*)d_in[7];
    const float* W    = (const float*)d_in[8];
    const float* bias = (const float*)d_in[9];
    const float* Wres = (const float*)d_in[10];
    const float* bres = (const float*)d_in[11];
    float* out = (float*)d_out;
    char* ws = (char*)d_ws;

    // ws layout (bytes, 16B-aligned), total ~25 MB
    f16*   Sb    = (f16*)(ws + 0);             //  6,291,456  [24][2048][64]
    f16*   Tb    = (f16*)(ws + 6291456);       //  6,291,456  [24][2048][64]
    f16*   suppT = (f16*)(ws + 12582912);      //  4,194,304  [32][32][2048]
    float* resd  = (float*)(ws + 16777216);    //  8,192,000  [32][2000][32]

    hipLaunchKernelGGL(k_prep, dim3(NNP), dim3(HH), 0, stream,
                       envf, Wenv, benv, src, tgt, Sb, Tb);
    hipLaunchKernelGGL(k_suppT, dim3(NB * NNP / 256), dim3(256), 0, stream,
                       x, W, Wres, bres, suppT, resd);
    hipLaunchKernelGGL(k_conv2, dim3(NT * NP * BCH), dim3(256), 0, stream,
                       Sb, Tb, suppT, adj, resd, bias, cyc, out);
}

// Round 6
// 294.568 us; speedup vs baseline: 1.3276x; 1.1633x over previous
//
#include <hip/hip_runtime.h>
#include <hip/hip_bf16.h>
#include <cstdint>

#define NN 2000   // nodes
#define NNP 2048  // padded nodes
#define NB 32     // batch
#define DD 32     // d_in == d_out
#define HH 64     // hidden
#define EE 16     // env features
#define NP 24     // periods
#define NT 32     // n-tiles of 64 (covers 2048)
#define LSTR 68   // LDS row stride in f16 elems

typedef _Float16 f16;
typedef _Float16 half8 __attribute__((ext_vector_type(8)));
typedef _Float16 half4v __attribute__((ext_vector_type(4)));
typedef float f32x4 __attribute__((ext_vector_type(4)));

// ---- prologue A: env = relu(envf@Wenv+b); Sb/Tb[n][p][h] = f16(src/tgt + env) ----
__global__ __launch_bounds__(64) void k_prep(const float* __restrict__ envf,
                                             const float* __restrict__ Wenv,
                                             const float* __restrict__ benv,
                                             const float* __restrict__ src,
                                             const float* __restrict__ tgt,
                                             f16* __restrict__ Sb,
                                             f16* __restrict__ Tb) {
    int n = blockIdx.x, h = threadIdx.x;
    if (n >= NN) {                              // zero the pad rows 2000..2047
        for (int p = 0; p < NP; ++p) {
            size_t o = ((size_t)n * NP + p) * HH + h;
            Sb[o] = (f16)0.f; Tb[o] = (f16)0.f;
        }
        return;
    }
    float acc = benv[h];
#pragma unroll
    for (int e = 0; e < EE; ++e) acc = fmaf(envf[n * EE + e], Wenv[e * HH + h], acc);
    acc = fmaxf(acc, 0.f);
    for (int p = 0; p < NP; ++p) {
        size_t i = ((size_t)p * NN + n) * HH + h;
        size_t o = ((size_t)n * NP + p) * HH + h;
        Sb[o] = (f16)(src[i] + acc);
        Tb[o] = (f16)(tgt[i] + acc);
    }
}

// ---- prologue B: suppT[b][m][k] = f16(x@W), k zero-padded; resd = relu(x@Wres+bres) f32 ----
__global__ __launch_bounds__(256) void k_suppT(const float* __restrict__ x,
                                               const float* __restrict__ W,
                                               const float* __restrict__ Wres,
                                               const float* __restrict__ bres,
                                               f16* __restrict__ suppT,
                                               float* __restrict__ resd) {
    __shared__ float w[DD * DD], wr[DD * DD];
    for (int i = threadIdx.x; i < DD * DD; i += 256) { w[i] = W[i]; wr[i] = Wres[i]; }
    __syncthreads();
    int idx = blockIdx.x * 256 + threadIdx.x;   // b*2048 + node
    int b = idx >> 11, node = idx & (NNP - 1);
    if (node >= NN) {                           // zero-pad k dim
#pragma unroll
        for (int m = 0; m < DD; ++m) suppT[((size_t)b * DD + m) * NNP + node] = (f16)0.f;
        return;
    }
    float xv[DD];
    const float4* xr = (const float4*)(x + ((size_t)b * NN + node) * DD);
#pragma unroll
    for (int q = 0; q < DD / 4; ++q) {
        float4 v = xr[q];
        xv[4 * q] = v.x; xv[4 * q + 1] = v.y; xv[4 * q + 2] = v.z; xv[4 * q + 3] = v.w;
    }
    float sa[DD], ra[DD];
#pragma unroll
    for (int m = 0; m < DD; ++m) { sa[m] = 0.f; ra[m] = bres[m]; }
#pragma unroll
    for (int d = 0; d < DD; ++d) {
        float xd = xv[d];
#pragma unroll
        for (int m = 0; m < DD; ++m) {
            sa[m] = fmaf(xd, w[d * DD + m], sa[m]);
            ra[m] = fmaf(xd, wr[d * DD + m], ra[m]);
        }
    }
#pragma unroll
    for (int m = 0; m < DD; ++m)                // per-m coalesced along node
        suppT[((size_t)b * DD + m) * NNP + node] = (f16)sa[m];
    float4* ro = (float4*)(resd + ((size_t)b * NN + node) * DD);
#pragma unroll
    for (int q = 0; q < DD / 4; ++q)
        ro[q] = make_float4(fmaxf(ra[4 * q], 0.f), fmaxf(ra[4 * q + 1], 0.f),
                            fmaxf(ra[4 * q + 2], 0.f), fmaxf(ra[4 * q + 3], 0.f));
}

// ---- main: one block per (n-tile, batch); fused S·T^T -> relu*adj -> ·supp ----
__global__ __launch_bounds__(256) void k_conv2(const f16* __restrict__ Sb,    // [NNP,NP,HH]
                                               const f16* __restrict__ Tb,    // [NNP,NP,HH]
                                               const f16* __restrict__ suppT, // [NB,DD,NNP]
                                               const float* __restrict__ adj, // [NN,NN]
                                               const float* __restrict__ resd,// [NB,NN,DD]
                                               const float* __restrict__ bias,// [DD]
                                               const int* __restrict__ cyc,   // [NB]
                                               float* __restrict__ out) {
    int bi = blockIdx.x;
    int nt = bi >> 5, b = bi & 31;   // b fastest: co-resident blocks share adj n-panel in L2
    int p = cyc[b] % NP; if (p < 0) p += NP;

    __shared__ f16 Tt[64][LSTR];
    __shared__ f16 Pt[64][LSTR];
    __shared__ f16 Sup[DD][LSTR];

    int t = threadIdx.x;
    int w = t >> 6, l = t & 63;
    int u = l & 15, g = l >> 4;      // MFMA lane decomposition
    int wm = w * 16;                 // wave's 16-row slice
    int n0 = nt * 64;

    // GEMM1 A-fragments (S rows), invariant over k-loop. k-map: h = 32s + 8g + j
    const f16* sbase = Sb + ((size_t)(n0 + wm + u) * NP + p) * HH + 8 * g;
    half8 af0 = *(const half8*)(sbase);
    half8 af1 = *(const half8*)(sbase + 32);

    float bias0 = bias[u], bias1 = bias[16 + u];
    f32x4 acc0 = (f32x4){0.f, 0.f, 0.f, 0.f};
    f32x4 acc1 = (f32x4){0.f, 0.f, 0.f, 0.f};

    for (int kt = 0; kt < NNP / 64; ++kt) {
        int k0 = kt * 64;
        __syncthreads();                        // prev iter done reading LDS
        {   // stage Tt: 64 rows x 128B; 4 threads/row x 16 f16 (full row)
            int row = t >> 2, ch = t & 3;
            const half4v* gp = (const half4v*)(Tb + ((size_t)(k0 + row) * NP + p) * HH + ch * 16);
            half4v v0 = gp[0], v1 = gp[1], v2 = gp[2], v3 = gp[3];
            *(half4v*)&Tt[row][ch * 16]      = v0;
            *(half4v*)&Tt[row][ch * 16 + 4]  = v1;
            *(half4v*)&Tt[row][ch * 16 + 8]  = v2;
            *(half4v*)&Tt[row][ch * 16 + 12] = v3;
        }
        {   // stage Sup: 32 rows x 128B; 8 threads/row x 8 f16
            int m = t >> 3, ch = t & 7;
            const half4v* gp = (const half4v*)(suppT + ((size_t)b * DD + m) * NNP + k0 + ch * 8);
            half4v v0 = gp[0], v1 = gp[1];
            *(half4v*)&Sup[m][ch * 8] = v0;
            *(half4v*)&Sup[m][ch * 8 + 4] = v1;
        }
        __syncthreads();
        // GEMM1: P = S·T^T over h (K=64 = 2 MFMA), then relu*adj -> Pt (f16)
#pragma unroll
        for (int cc = 0; cc < 4; ++cc) {
            half4v b0lo = *(const half4v*)&Tt[16 * cc + u][8 * g];
            half4v b0hi = *(const half4v*)&Tt[16 * cc + u][8 * g + 4];
            half4v b1lo = *(const half4v*)&Tt[16 * cc + u][32 + 8 * g];
            half4v b1hi = *(const half4v*)&Tt[16 * cc + u][32 + 8 * g + 4];
            half8 bf0 = {b0lo[0], b0lo[1], b0lo[2], b0lo[3], b0hi[0], b0hi[1], b0hi[2], b0hi[3]};
            half8 bf1 = {b1lo[0], b1lo[1], b1lo[2], b1lo[3], b1hi[0], b1hi[1], b1hi[2], b1hi[3]};
            f32x4 pacc = (f32x4){0.f, 0.f, 0.f, 0.f};
            pacc = __builtin_amdgcn_mfma_f32_16x16x32_f16(af0, bf0, pacc, 0, 0, 0);
            pacc = __builtin_amdgcn_mfma_f32_16x16x32_f16(af1, bf1, pacc, 0, 0, 0);
            int kcol = k0 + 16 * cc + u;
#pragma unroll
            for (int r = 0; r < 4; ++r) {       // D layout: row = 4g+r, col = u (m89)
                int nrow = n0 + wm + 4 * g + r;
                float av = 0.f;
                if (nrow < NN && kcol < NN) av = adj[(size_t)nrow * NN + kcol];
                Pt[wm + 4 * g + r][16 * cc + u] = (f16)(fmaxf(pacc[r], 0.f) * av);
            }
        }
        __syncthreads();
        // GEMM2: acc += Pt · Sup  (K=64 = 2 MFMA steps, 2 output col-halves)
#pragma unroll
        for (int s = 0; s < 2; ++s) {
            half4v plo = *(const half4v*)&Pt[wm + u][32 * s + 8 * g];
            half4v phi = *(const half4v*)&Pt[wm + u][32 * s + 8 * g + 4];
            half8 paf = {plo[0], plo[1], plo[2], plo[3], phi[0], phi[1], phi[2], phi[3]};
            {
                half4v slo = *(const half4v*)&Sup[u][32 * s + 8 * g];
                half4v shi = *(const half4v*)&Sup[u][32 * s + 8 * g + 4];
                half8 sbf = {slo[0], slo[1], slo[2], slo[3], shi[0], shi[1], shi[2], shi[3]};
                acc0 = __builtin_amdgcn_mfma_f32_16x16x32_f16(paf, sbf, acc0, 0, 0, 0);
            }
            {
                half4v slo = *(const half4v*)&Sup[16 + u][32 * s + 8 * g];
                half4v shi = *(const half4v*)&Sup[16 + u][32 * s + 8 * g + 4];
                half8 sbf = {slo[0], slo[1], slo[2], slo[3], shi[0], shi[1], shi[2], shi[3]};
                acc1 = __builtin_amdgcn_mfma_f32_16x16x32_f16(paf, sbf, acc1, 0, 0, 0);
            }
        }
    }
    // epilogue: out = relu(acc + bias + resd)
#pragma unroll
    for (int r = 0; r < 4; ++r) {
        int nrow = n0 + wm + 4 * g + r;
        if (nrow < NN) {
            size_t o = ((size_t)b * NN + nrow) * DD + u;
            out[o]      = fmaxf(acc0[r] + bias0 + resd[o], 0.f);
            out[o + 16] = fmaxf(acc1[r] + bias1 + resd[o + 16], 0.f);
        }
    }
}

extern "C" void kernel_launch(void* const* d_in, const int* in_sizes, int n_in,
                              void* d_out, int out_size, void* d_ws, size_t ws_size,
                              hipStream_t stream) {
    const float* x    = (const float*)d_in[0];
    const int*   cyc  = (const int*)d_in[1];
    const float* adj  = (const float*)d_in[2];
    const float* envf = (const float*)d_in[3];
    const float* Wenv = (const float*)d_in[4];
    const float* benv = (const float*)d_in[5];
    const float* src  = (const float*)d_in[6];
    const float* tgt  = (const float*)d_in[7];
    const float* W    = (const float*)d_in[8];
    const float* bias = (const float*)d_in[9];
    const float* Wres = (const float*)d_in[10];
    const float* bres = (const float*)d_in[11];
    float* out = (float*)d_out;
    char* ws = (char*)d_ws;

    // ws layout (bytes, 16B-aligned), total ~25 MB
    f16*   Sb    = (f16*)(ws + 0);             //  6,291,456  [2048][24][64]
    f16*   Tb    = (f16*)(ws + 6291456);       //  6,291,456  [2048][24][64]
    f16*   suppT = (f16*)(ws + 12582912);      //  4,194,304  [32][32][2048]
    float* resd  = (float*)(ws + 16777216);    //  8,192,000  [32][2000][32]

    hipLaunchKernelGGL(k_prep, dim3(NNP), dim3(HH), 0, stream,
                       envf, Wenv, benv, src, tgt, Sb, Tb);
    hipLaunchKernelGGL(k_suppT, dim3(NB * NNP / 256), dim3(256), 0, stream,
                       x, W, Wres, bres, suppT, resd);
    hipLaunchKernelGGL(k_conv2, dim3(NT * NB), dim3(256), 0, stream,
                       Sb, Tb, suppT, adj, resd, bias, cyc, out);
}

// Round 7
// 200.848 us; speedup vs baseline: 1.9471x; 1.4666x over previous
//
#include <hip/hip_runtime.h>
#include <hip/hip_bf16.h>
#include <cstdint>

#define NN 2000   // nodes
#define NNP 2048  // padded nodes
#define NB 32     // batch
#define DD 32     // d_in == d_out
#define HH 64     // hidden
#define EE 16     // env features
#define NP 24     // periods
#define NT 32     // n-tiles of 64 (covers 2048)
#define KSPLIT 2  // k-range split per output tile
#define KITERS (NNP / 64 / KSPLIT)
#define LSTR 68   // LDS row stride in f16 elems

typedef _Float16 f16;
typedef _Float16 half8 __attribute__((ext_vector_type(8)));
typedef _Float16 half4v __attribute__((ext_vector_type(4)));
typedef float f32x4 __attribute__((ext_vector_type(4)));

// ---- prologue A: env = relu(envf@Wenv+b); Sb/Tb[n][p][h] = f16(src/tgt + env) ----
__global__ __launch_bounds__(64) void k_prep(const float* __restrict__ envf,
                                             const float* __restrict__ Wenv,
                                             const float* __restrict__ benv,
                                             const float* __restrict__ src,
                                             const float* __restrict__ tgt,
                                             f16* __restrict__ Sb,
                                             f16* __restrict__ Tb) {
    int n = blockIdx.x, h = threadIdx.x;
    if (n >= NN) {                              // zero the pad rows 2000..2047
        for (int p = 0; p < NP; ++p) {
            size_t o = ((size_t)n * NP + p) * HH + h;
            Sb[o] = (f16)0.f; Tb[o] = (f16)0.f;
        }
        return;
    }
    float acc = benv[h];
#pragma unroll
    for (int e = 0; e < EE; ++e) acc = fmaf(envf[n * EE + e], Wenv[e * HH + h], acc);
    acc = fmaxf(acc, 0.f);
    for (int p = 0; p < NP; ++p) {
        size_t i = ((size_t)p * NN + n) * HH + h;
        size_t o = ((size_t)n * NP + p) * HH + h;
        Sb[o] = (f16)(src[i] + acc);
        Tb[o] = (f16)(tgt[i] + acc);
    }
}

// ---- prologue B: suppT[b][m][k] = f16(x@W), k zero-padded; resd = relu(x@Wres+bres) f32 ----
__global__ __launch_bounds__(256) void k_suppT(const float* __restrict__ x,
                                               const float* __restrict__ W,
                                               const float* __restrict__ Wres,
                                               const float* __restrict__ bres,
                                               f16* __restrict__ suppT,
                                               float* __restrict__ resd) {
    __shared__ float w[DD * DD], wr[DD * DD];
    for (int i = threadIdx.x; i < DD * DD; i += 256) { w[i] = W[i]; wr[i] = Wres[i]; }
    __syncthreads();
    int idx = blockIdx.x * 256 + threadIdx.x;   // b*2048 + node
    int b = idx >> 11, node = idx & (NNP - 1);
    if (node >= NN) {                           // zero-pad k dim
#pragma unroll
        for (int m = 0; m < DD; ++m) suppT[((size_t)b * DD + m) * NNP + node] = (f16)0.f;
        return;
    }
    float xv[DD];
    const float4* xr = (const float4*)(x + ((size_t)b * NN + node) * DD);
#pragma unroll
    for (int q = 0; q < DD / 4; ++q) {
        float4 v = xr[q];
        xv[4 * q] = v.x; xv[4 * q + 1] = v.y; xv[4 * q + 2] = v.z; xv[4 * q + 3] = v.w;
    }
    float sa[DD], ra[DD];
#pragma unroll
    for (int m = 0; m < DD; ++m) { sa[m] = 0.f; ra[m] = bres[m]; }
#pragma unroll
    for (int d = 0; d < DD; ++d) {
        float xd = xv[d];
#pragma unroll
        for (int m = 0; m < DD; ++m) {
            sa[m] = fmaf(xd, w[d * DD + m], sa[m]);
            ra[m] = fmaf(xd, wr[d * DD + m], ra[m]);
        }
    }
#pragma unroll
    for (int m = 0; m < DD; ++m)                // per-m coalesced along node
        suppT[((size_t)b * DD + m) * NNP + node] = (f16)sa[m];
    float4* ro = (float4*)(resd + ((size_t)b * NN + node) * DD);
#pragma unroll
    for (int q = 0; q < DD / 4; ++q)
        ro[q] = make_float4(fmaxf(ra[4 * q], 0.f), fmaxf(ra[4 * q + 1], 0.f),
                            fmaxf(ra[4 * q + 2], 0.f), fmaxf(ra[4 * q + 3], 0.f));
}

// ---- main: one block per (n-tile, ks, batch); split-K, atomic accumulate ----
__global__ __launch_bounds__(256) void k_conv2(const f16* __restrict__ Sb,    // [NNP,NP,HH]
                                               const f16* __restrict__ Tb,    // [NNP,NP,HH]
                                               const f16* __restrict__ suppT, // [NB,DD,NNP]
                                               const float* __restrict__ adj, // [NN,NN]
                                               const int* __restrict__ cyc,   // [NB]
                                               float* __restrict__ accbuf) {  // [NB,NNP,DD] f32
    int bi = blockIdx.x;
    int b = bi & 31;                 // b fastest: co-resident blocks share adj n-panel in L2
    int ks = (bi >> 5) & (KSPLIT - 1);
    int nt = bi >> 6;
    int p = cyc[b] % NP; if (p < 0) p += NP;

    __shared__ f16 Tt[64][LSTR];
    __shared__ f16 Pt[64][LSTR];
    __shared__ f16 Sup[DD][LSTR];

    int t = threadIdx.x;
    int w = t >> 6, l = t & 63;
    int u = l & 15, g = l >> 4;      // MFMA lane decomposition
    int wm = w * 16;                 // wave's 16-row slice
    int n0 = nt * 64;

    // GEMM1 A-fragments (S rows), invariant over k-loop. k-map: h = 32s + 8g + j
    const f16* sbase = Sb + ((size_t)(n0 + wm + u) * NP + p) * HH + 8 * g;
    half8 af0 = *(const half8*)(sbase);
    half8 af1 = *(const half8*)(sbase + 32);

    f32x4 acc0 = (f32x4){0.f, 0.f, 0.f, 0.f};
    f32x4 acc1 = (f32x4){0.f, 0.f, 0.f, 0.f};

    for (int kl = 0; kl < KITERS; ++kl) {
        int k0 = (ks * KITERS + kl) * 64;
        // adj register-prefetch: independent of LDS, overlaps the stage drain
        float av[4][4];
#pragma unroll
        for (int cc = 0; cc < 4; ++cc) {
            int kcol = k0 + 16 * cc + u;
#pragma unroll
            for (int r = 0; r < 4; ++r) {
                int nrow = n0 + wm + 4 * g + r;
                av[cc][r] = (nrow < NN && kcol < NN) ? adj[(size_t)nrow * NN + kcol] : 0.f;
            }
        }
        __syncthreads();                        // prev iter done reading LDS
        {   // stage Tt: 64 rows x 128B; 4 threads/row x 16 f16 (full row)
            int row = t >> 2, ch = t & 3;
            const half4v* gp = (const half4v*)(Tb + ((size_t)(k0 + row) * NP + p) * HH + ch * 16);
            half4v v0 = gp[0], v1 = gp[1], v2 = gp[2], v3 = gp[3];
            *(half4v*)&Tt[row][ch * 16]      = v0;
            *(half4v*)&Tt[row][ch * 16 + 4]  = v1;
            *(half4v*)&Tt[row][ch * 16 + 8]  = v2;
            *(half4v*)&Tt[row][ch * 16 + 12] = v3;
        }
        {   // stage Sup: 32 rows x 128B; 8 threads/row x 8 f16
            int m = t >> 3, ch = t & 7;
            const half4v* gp = (const half4v*)(suppT + ((size_t)b * DD + m) * NNP + k0 + ch * 8);
            half4v v0 = gp[0], v1 = gp[1];
            *(half4v*)&Sup[m][ch * 8] = v0;
            *(half4v*)&Sup[m][ch * 8 + 4] = v1;
        }
        __syncthreads();
        // GEMM1: P = S·T^T over h (K=64 = 2 MFMA), then relu*adj -> Pt (f16)
#pragma unroll
        for (int cc = 0; cc < 4; ++cc) {
            half4v b0lo = *(const half4v*)&Tt[16 * cc + u][8 * g];
            half4v b0hi = *(const half4v*)&Tt[16 * cc + u][8 * g + 4];
            half4v b1lo = *(const half4v*)&Tt[16 * cc + u][32 + 8 * g];
            half4v b1hi = *(const half4v*)&Tt[16 * cc + u][32 + 8 * g + 4];
            half8 bf0 = {b0lo[0], b0lo[1], b0lo[2], b0lo[3], b0hi[0], b0hi[1], b0hi[2], b0hi[3]};
            half8 bf1 = {b1lo[0], b1lo[1], b1lo[2], b1lo[3], b1hi[0], b1hi[1], b1hi[2], b1hi[3]};
            f32x4 pacc = (f32x4){0.f, 0.f, 0.f, 0.f};
            pacc = __builtin_amdgcn_mfma_f32_16x16x32_f16(af0, bf0, pacc, 0, 0, 0);
            pacc = __builtin_amdgcn_mfma_f32_16x16x32_f16(af1, bf1, pacc, 0, 0, 0);
#pragma unroll
            for (int r = 0; r < 4; ++r)         // D layout: row = 4g+r, col = u (m89)
                Pt[wm + 4 * g + r][16 * cc + u] = (f16)(fmaxf(pacc[r], 0.f) * av[cc][r]);
        }
        __syncthreads();
        // GEMM2: acc += Pt · Sup  (K=64 = 2 MFMA steps, 2 output col-halves)
#pragma unroll
        for (int s = 0; s < 2; ++s) {
            half4v plo = *(const half4v*)&Pt[wm + u][32 * s + 8 * g];
            half4v phi = *(const half4v*)&Pt[wm + u][32 * s + 8 * g + 4];
            half8 paf = {plo[0], plo[1], plo[2], plo[3], phi[0], phi[1], phi[2], phi[3]};
            {
                half4v slo = *(const half4v*)&Sup[u][32 * s + 8 * g];
                half4v shi = *(const half4v*)&Sup[u][32 * s + 8 * g + 4];
                half8 sbf = {slo[0], slo[1], slo[2], slo[3], shi[0], shi[1], shi[2], shi[3]};
                acc0 = __builtin_amdgcn_mfma_f32_16x16x32_f16(paf, sbf, acc0, 0, 0, 0);
            }
            {
                half4v slo = *(const half4v*)&Sup[16 + u][32 * s + 8 * g];
                half4v shi = *(const half4v*)&Sup[16 + u][32 * s + 8 * g + 4];
                half8 sbf = {slo[0], slo[1], slo[2], slo[3], shi[0], shi[1], shi[2], shi[3]};
                acc1 = __builtin_amdgcn_mfma_f32_16x16x32_f16(paf, sbf, acc1, 0, 0, 0);
            }
        }
    }
    // epilogue: atomic accumulate into accbuf (pad rows hold zeros, harmless)
#pragma unroll
    for (int r = 0; r < 4; ++r) {
        int nrow = n0 + wm + 4 * g + r;
        size_t o = ((size_t)b * NNP + nrow) * DD + u;
        atomicAdd(&accbuf[o], acc0[r]);
        atomicAdd(&accbuf[o + 16], acc1[r]);
    }
}

// ---- finalize: out = relu(accbuf + bias + resd) ----
__global__ __launch_bounds__(256) void k_fin(const float* __restrict__ accbuf,
                                             const float* __restrict__ resd,
                                             const float* __restrict__ bias,
                                             float* __restrict__ out) {
    int idx = blockIdx.x * 256 + threadIdx.x;   // float4 units over [NB][NN][DD]
    if (idx >= NB * NN * (DD / 4)) return;
    int m4 = idx & 7;
    int n = (idx >> 3) % NN;
    int b = idx / (NN * 8);
    float4 a = ((const float4*)accbuf)[((size_t)b * NNP + n) * 8 + m4];
    float4 rs = ((const float4*)resd)[(size_t)idx];
    float4 bv = ((const float4*)bias)[m4];
    float4 o = make_float4(fmaxf(a.x + bv.x + rs.x, 0.f), fmaxf(a.y + bv.y + rs.y, 0.f),
                           fmaxf(a.z + bv.z + rs.z, 0.f), fmaxf(a.w + bv.w + rs.w, 0.f));
    ((float4*)out)[(size_t)idx] = o;
}

extern "C" void kernel_launch(void* const* d_in, const int* in_sizes, int n_in,
                              void* d_out, int out_size, void* d_ws, size_t ws_size,
                              hipStream_t stream) {
    const float* x    = (const float*)d_in[0];
    const int*   cyc  = (const int*)d_in[1];
    const float* adj  = (const float*)d_in[2];
    const float* envf = (const float*)d_in[3];
    const float* Wenv = (const float*)d_in[4];
    const float* benv = (const float*)d_in[5];
    const float* src  = (const float*)d_in[6];
    const float* tgt  = (const float*)d_in[7];
    const float* W    = (const float*)d_in[8];
    const float* bias = (const float*)d_in[9];
    const float* Wres = (const float*)d_in[10];
    const float* bres = (const float*)d_in[11];
    float* out = (float*)d_out;
    char* ws = (char*)d_ws;

    // ws layout (bytes, 16B-aligned), total ~33.4 MB
    f16*   Sb     = (f16*)(ws + 0);            //  6,291,456  [2048][24][64]
    f16*   Tb     = (f16*)(ws + 6291456);      //  6,291,456  [2048][24][64]
    f16*   suppT  = (f16*)(ws + 12582912);     //  4,194,304  [32][32][2048]
    float* resd   = (float*)(ws + 16777216);   //  8,192,000  [32][2000][32]
    float* accbuf = (float*)(ws + 24969216);   //  8,388,608  [32][2048][32]

    hipMemsetAsync(accbuf, 0, (size_t)NB * NNP * DD * 4, stream);
    hipLaunchKernelGGL(k_prep, dim3(NNP), dim3(HH), 0, stream,
                       envf, Wenv, benv, src, tgt, Sb, Tb);
    hipLaunchKernelGGL(k_suppT, dim3(NB * NNP / 256), dim3(256), 0, stream,
                       x, W, Wres, bres, suppT, resd);
    hipLaunchKernelGGL(k_conv2, dim3(NT * KSPLIT * NB), dim3(256), 0, stream,
                       Sb, Tb, suppT, adj, cyc, accbuf);
    hipLaunchKernelGGL(k_fin, dim3((NB * NN * (DD / 4) + 255) / 256), dim3(256), 0, stream,
                       accbuf, resd, bias, out);
}